// Round 7
// baseline (269.172 us; speedup 1.0000x reference)
//
#include <hip/hip_runtime.h>
#include <hip/hip_bf16.h>

// Problem: B=4, C=256, N=4096 (16^3).
// out[b,c,n] = sum_m relu(cos(x_n,x_m))^2 * (W x + b)[c,m]
// xn = x/||x|| (bf16) -> S^T = xn_m . xn_n (swapped, 32x32x16 MFMA) ->
// P = relu(S)^2 lane-local -> cvt_pk+permlane32_swap -> PV A-frags ->
// oacc += PA . V (V = tb^T). P never leaves the wave: no LDS/barriers in loop.

typedef unsigned short u16;
typedef __attribute__((ext_vector_type(8))) short short8;    // 8 bf16
typedef __attribute__((ext_vector_type(4))) float f32x4;
typedef __attribute__((ext_vector_type(16))) float f32x16;
typedef __attribute__((ext_vector_type(4))) int int4v;

#define MFMA16(a, b, c) __builtin_amdgcn_mfma_f32_16x16x32_bf16((a), (b), (c), 0, 0, 0)
#define MFMA32(a, b, c) __builtin_amdgcn_mfma_f32_32x32x16_bf16((a), (b), (c), 0, 0, 0)

__device__ __forceinline__ u16 f2bf(float f) {
    union { float f; unsigned u; } v; v.f = f;
    unsigned u = v.u;
    u += 0x7fffu + ((u >> 16) & 1u);   // RNE
    return (u16)(u >> 16);
}

__device__ __forceinline__ unsigned cvtpk(float lo, float hi) {
    unsigned r;
    asm("v_cvt_pk_bf16_f32 %0, %1, %2" : "=v"(r) : "v"(lo), "v"(hi));
    return r;
}

// ------- K1: fused norm + transpose + W-convert: one read of x ---------------
__global__ __launch_bounds__(256) void k_prep(const float* __restrict__ x,
                                              const float* __restrict__ W,
                                              u16* __restrict__ xfn,
                                              u16* __restrict__ Wbf,
                                              float* __restrict__ nrm) {
    __shared__ float xs[256][65];
    __shared__ float part[4][64];
    __shared__ float rs_s[64];
    int bid = blockIdx.x;
    int b = bid >> 6, n0 = (bid & 63) << 6;
    int tid = threadIdx.x;
    int wi = (bid << 8) + tid;
    Wbf[wi] = f2bf(W[wi]);
    int rowg = tid >> 4, l16 = tid & 15;
    const float* xb = x + ((size_t)b << 20) + n0;
#pragma unroll
    for (int s = 0; s < 16; ++s) {
        int row = (s << 4) + rowg;
        float4 v = *(const float4*)(xb + (size_t)row * 4096 + (l16 << 2));
        xs[row][(l16 << 2) + 0] = v.x;
        xs[row][(l16 << 2) + 1] = v.y;
        xs[row][(l16 << 2) + 2] = v.z;
        xs[row][(l16 << 2) + 3] = v.w;
    }
    __syncthreads();
    int q = tid >> 6, nl = tid & 63;
    float ss = 0.f;
#pragma unroll 16
    for (int c = 0; c < 64; ++c) {
        float v = xs[(q << 6) + c][nl];
        ss += v * v;
    }
    part[q][nl] = ss;
    __syncthreads();
    if (tid < 64) {
        float t = part[0][tid] + part[1][tid] + part[2][tid] + part[3][tid];
        float nr = sqrtf(t);
        nrm[(b << 12) + n0 + tid] = nr;
        rs_s[tid] = 1.0f / fmaxf(nr, 1e-8f);
    }
    __syncthreads();
    u16* op = xfn + ((size_t)b << 20) + (size_t)n0 * 256;
#pragma unroll
    for (int s2 = 0; s2 < 4; ++s2) {
        int n = (s2 << 4) + rowg;
        float rsv = rs_s[n];
        u16 tmp[16];
#pragma unroll
        for (int j = 0; j < 16; ++j)
            tmp[j] = f2bf(xs[(l16 << 4) + j][n] * rsv);
        *(short8*)(op + (size_t)n * 256 + (l16 << 4)) = *(const short8*)(&tmp[0]);
        *(short8*)(op + (size_t)n * 256 + (l16 << 4) + 8) = *(const short8*)(&tmp[8]);
    }
}

// ---------------- K2: tb[b][c][n] = nrm[n]*(W xn)[c,n] + bias[c] ------------
__global__ __launch_bounds__(256) void k_tgemm(const u16* __restrict__ Wbf,
                                               const u16* __restrict__ xfn,
                                               const float* __restrict__ bias,
                                               const float* __restrict__ nrm,
                                               u16* __restrict__ tb) {
    int bid = blockIdx.x;
    int batch = bid >> 7, nt = bid & 127;
    int n0 = nt << 5;
    const u16* xf_b = xfn + ((size_t)batch << 20);
    u16* tb_b = tb + ((size_t)batch << 20);
    int tid = threadIdx.x, wid = tid >> 6, lane = tid & 63, lg = lane >> 4, lr = lane & 15;

    f32x4 zero = {0.f, 0.f, 0.f, 0.f};
    f32x4 acc[4][2];
#pragma unroll
    for (int ci = 0; ci < 4; ++ci)
#pragma unroll
        for (int nj = 0; nj < 2; ++nj) acc[ci][nj] = zero;

#pragma unroll
    for (int kc = 0; kc < 8; ++kc) {
        short8 bfr[2], afr[4];
#pragma unroll
        for (int nj = 0; nj < 2; ++nj)
            bfr[nj] = *(const short8*)(xf_b + (size_t)(n0 + (nj << 4) + lr) * 256 + (kc << 5) + (lg << 3));
#pragma unroll
        for (int ci = 0; ci < 4; ++ci)
            afr[ci] = *(const short8*)(Wbf + (size_t)((wid << 6) + (ci << 4) + lr) * 256 + (kc << 5) + (lg << 3));
#pragma unroll
        for (int ci = 0; ci < 4; ++ci) {
            acc[ci][0] = MFMA16(afr[ci], bfr[0], acc[ci][0]);
            acc[ci][1] = MFMA16(afr[ci], bfr[1], acc[ci][1]);
        }
    }
    float nrmv[2];
#pragma unroll
    for (int nj = 0; nj < 2; ++nj)
        nrmv[nj] = nrm[(batch << 12) + n0 + (nj << 4) + lr];
#pragma unroll
    for (int ci = 0; ci < 4; ++ci) {
        int cb = (wid << 6) + (ci << 4) + (lg << 2);
#pragma unroll
        for (int r = 0; r < 4; ++r) {
            float bv = bias[cb + r];
#pragma unroll
            for (int nj = 0; nj < 2; ++nj)
                tb_b[(size_t)(cb + r) * 4096 + n0 + (nj << 4) + lr] = f2bf(acc[ci][nj][r] * nrmv[nj] + bv);
        }
    }
}

// ---------------- K3: fused, barrier-free main loop -------------------------
// 256 blocks (1/CU), 256 threads = 4 waves, 1/SIMD. Block owns n-tile 64.
// Wave (nh, mh): n-half nh (32 rows), m-half mh (2048 m). Per 32-m tile:
//   S^T = mfma32(A=xn_m, B=xn_n) x16 (2 chains)  -> lane holds P[n=l31][16 m]
//   P = relu^2 -> cvt_pk -> permlane32_swap -> PA words (A-op m-layout)
//   oacc[ct] += mfma32(PA[kb], V[ct][kb]) , V = tb^T streamed in kb-halves.
// No LDS, no barriers in loop. Epilogue: mh-pair reduction via LDS + store.
__global__ __launch_bounds__(256) void k_fused(const u16* __restrict__ xfn,
                                               const u16* __restrict__ tb,
                                               float* __restrict__ out) {
    __shared__ float red[256][68];   // 69.6 KB, 16B-aligned rows

    int bid = blockIdx.x;
    int xcd = bid & 7, grp = bid >> 3;
    int batch = xcd >> 1;
    int nt = grp + 32 * (xcd & 1);
    int n0 = nt << 6;

    const u16* xf_b = xfn + ((size_t)batch << 20);
    const u16* tb_b = tb + ((size_t)batch << 20);
    float* out_b = out + ((size_t)batch << 20);

    int tid = threadIdx.x;
    int wid = tid >> 6, lane = tid & 63;
    int l31 = lane & 31, hi = lane >> 5;
    int nh = wid >> 1, mh = wid & 1;

    // persistent B-frags: this wave's 32 n-rows, K=256 (64 VGPR)
    const u16* brow = xf_b + (size_t)(n0 + (nh << 5) + l31) * 256 + (hi << 3);
    short8 Bf[16];
#pragma unroll
    for (int kk = 0; kk < 16; ++kk) Bf[kk] = *(const short8*)(brow + (kk << 4));

    // A-frag stream: m-rows (mh*2048 + t*32 + l31)
    const u16* arow = xf_b + (size_t)((mh << 11) + l31) * 256 + (hi << 3);
    // V stream: V[m][c] = tb[c][m]; lane: c = ct*32 + l31, k = m0+kb*16+hi*8+j
    const u16* vrow = tb_b + (size_t)l31 * 4096 + (mh << 11) + (hi << 3);

    short8 Af[16];
#pragma unroll
    for (int kk = 0; kk < 16; ++kk) Af[kk] = *(const short8*)(arow + (kk << 4));
    short8 V0[8], V1[8];
#pragma unroll
    for (int ct = 0; ct < 8; ++ct) V0[ct] = *(const short8*)(vrow + ((size_t)ct << 17));

    f32x16 z16;
#pragma unroll
    for (int r = 0; r < 16; ++r) z16[r] = 0.f;
    f32x16 oa[8];
#pragma unroll
    for (int ct = 0; ct < 8; ++ct) oa[ct] = z16;

    for (int t = 0; t < 64; ++t) {
        int tn = (t < 63) ? t + 1 : 63;
        // 1. issue V kb1 of tile t (used at step 7; covered by S + PV-kb0)
        const u16* vcol_t = vrow + (t << 5);
#pragma unroll
        for (int ct = 0; ct < 8; ++ct)
            V1[ct] = *(const short8*)(vcol_t + ((size_t)ct << 17) + 16);
        // 2. S^T: 2 accumulator chains of 8
        f32x16 sa = MFMA32(Af[0], Bf[0], z16);
        f32x16 sb = MFMA32(Af[8], Bf[8], z16);
#pragma unroll
        for (int kk = 1; kk < 8; ++kk) {
            sa = MFMA32(Af[kk], Bf[kk], sa);
            sb = MFMA32(Af[kk + 8], Bf[kk + 8], sb);
        }
        // 3. issue A-frags for tile t+1 (used next body; covered by 4-7)
        const u16* arow_n = arow + ((size_t)tn << 13);
#pragma unroll
        for (int kk = 0; kk < 16; ++kk) Af[kk] = *(const short8*)(arow_n + (kk << 4));
        // 4. P = relu(S)^2 ; pack to PV A-words via cvt_pk + permlane32_swap
        float p[16];
#pragma unroll
        for (int r = 0; r < 16; ++r) {
            float v = fmaxf(sa[r] + sb[r], 0.f);
            p[r] = v * v;
        }
        unsigned c01 = cvtpk(p[0], p[1]),   c23 = cvtpk(p[2], p[3]);
        unsigned c45 = cvtpk(p[4], p[5]),   c67 = cvtpk(p[6], p[7]);
        unsigned c89 = cvtpk(p[8], p[9]),   cab = cvtpk(p[10], p[11]);
        unsigned ccd = cvtpk(p[12], p[13]), cef = cvtpk(p[14], p[15]);
        // unzip lo/hi 32-lane halves: a' = {a.lo,b.lo}, b' = {a.hi,b.hi}
        asm("v_permlane32_swap_b32 %0, %1" : "+v"(c01), "+v"(c45));
        asm("v_permlane32_swap_b32 %0, %1" : "+v"(c23), "+v"(c67));
        asm("v_permlane32_swap_b32 %0, %1" : "+v"(c89), "+v"(ccd));
        asm("v_permlane32_swap_b32 %0, %1" : "+v"(cab), "+v"(cef));
        union { int4v i; short8 s; } u0, u1;
        u0.i = (int4v){(int)c01, (int)c23, (int)c45, (int)c67};   // kb0: m 0-15
        u1.i = (int4v){(int)c89, (int)cab, (int)ccd, (int)cef};   // kb1: m 16-31
        short8 pa0 = u0.s, pa1 = u1.s;
        // 5. PV kb0 (V0 loaded last body / prologue)
#pragma unroll
        for (int ct = 0; ct < 8; ++ct) oa[ct] = MFMA32(pa0, V0[ct], oa[ct]);
        // 6. issue V kb0 of tile t+1 (covered by PV-kb1 + next S)
        const u16* vcol_n = vrow + (tn << 5);
#pragma unroll
        for (int ct = 0; ct < 8; ++ct)
            V0[ct] = *(const short8*)(vcol_n + ((size_t)ct << 17));
        // 7. PV kb1
#pragma unroll
        for (int ct = 0; ct < 8; ++ct) oa[ct] = MFMA32(pa1, V1[ct], oa[ct]);
    }

    // ---- epilogue: mh-pair reduction + store --------------------------------
    // oacc layout: c = ct*32 + l31, n = n0 + nh*32 + (r&3) + 8*(r>>2) + 4*hi
    if (mh == 1) {
#pragma unroll
        for (int ct = 0; ct < 8; ++ct)
#pragma unroll
            for (int q = 0; q < 4; ++q) {
                f32x4 v = {oa[ct][4 * q + 0], oa[ct][4 * q + 1],
                           oa[ct][4 * q + 2], oa[ct][4 * q + 3]};
                *(f32x4*)&red[(ct << 5) + l31][(nh << 5) + (q << 3) + (hi << 2)] = v;
            }
    }
    __syncthreads();
    if (mh == 0) {
#pragma unroll
        for (int ct = 0; ct < 8; ++ct) {
            int c = (ct << 5) + l31;
#pragma unroll
            for (int q = 0; q < 4; ++q) {
                f32x4 v = *(const f32x4*)&red[c][(nh << 5) + (q << 3) + (hi << 2)];
                int n = n0 + (nh << 5) + (q << 3) + (hi << 2);
                f32x4 o = {oa[ct][4 * q + 0] + v[0], oa[ct][4 * q + 1] + v[1],
                           oa[ct][4 * q + 2] + v[2], oa[ct][4 * q + 3] + v[3]};
                *(f32x4*)(out_b + (size_t)c * 4096 + n) = o;
            }
        }
    }
}

extern "C" void kernel_launch(void* const* d_in, const int* in_sizes, int n_in,
                              void* d_out, int out_size, void* d_ws, size_t ws_size,
                              hipStream_t stream) {
    const float* x = (const float*)d_in[0];     // (4,256,16,16,16) fp32
    const float* W = (const float*)d_in[1];     // (256,256) fp32
    const float* bias = (const float*)d_in[2];  // (256,) fp32
    float* out = (float*)d_out;

    char* ws = (char*)d_ws;
    u16* xfn = (u16*)ws;                                   // 8 MiB: [B][N][C] bf16, normalized
    u16* tb = (u16*)(ws + ((size_t)8 << 20));              // 8 MiB: [B][C][N] bf16
    u16* Wbf = (u16*)(ws + ((size_t)16 << 20));            // 128 KiB
    float* nrm = (float*)(ws + ((size_t)16 << 20) + (192u << 10));  // 64 KiB

    hipLaunchKernelGGL(k_prep, dim3(256), dim3(256), 0, stream, x, W, xfn, Wbf, nrm);
    hipLaunchKernelGGL(k_tgemm, dim3(512), dim3(256), 0, stream, Wbf, xfn, bias, nrm, tb);
    hipLaunchKernelGGL(k_fused, dim3(256), dim3(256), 0, stream, xfn, tb, out);
}

// Round 8
// 85.754 us; speedup vs baseline: 3.1389x; 3.1389x over previous
//
#include <hip/hip_runtime.h>
#include <hip/hip_bf16.h>

// Problem: B=4, C=256, N=4096 (16^3).
// out[b,c,n] = sum_m relu(cos(x_n,x_m))^2 * (W x + b)[c,m]
// xn = x/||x|| (bf16) -> S = xn^T xn, P = relu(S)^2,
// T[c,m] = nrm[m]*(W xn)[c,m] + b[c],  out = T * P^T.
//
// KEY (r7 lesson): MFMA fragment loads from global with natural layouts are
// lane-strided (512B/8KB) -> 64 cache lines per instr -> line-request bound.
// Fix: FRAGMENT-MAJOR layouts (xff, Wf, tbf) where each load is
// base + lane*16B (1KB burst, 16 lines). All k_fused in-loop loads coalesced.
//
// xff chunk ((tile*4+rt)*8+kc): lane l -> xn row tile*64+rt*16+(l&15),
//                                cols kc*32+(l>>4)*8 .. +8      (512 u16/chunk)
// tbf chunk (tile*32+cq*8+ci*2+k2): lane l -> T row cq*64+ci*16+(l&15),
//                                col tile*64+k2*32+(l>>4)*8 .. +8
// Wf  chunk ((wq*4+ci)*8+kc): lane l -> W row wq*64+ci*16+(l&15),
//                                cols kc*32+(l>>4)*8 .. +8

typedef unsigned short u16;
typedef __attribute__((ext_vector_type(8))) short short8;   // 8 bf16 = 4 VGPRs
typedef __attribute__((ext_vector_type(4))) float f32x4;

#define MFMA16(a, b, c) __builtin_amdgcn_mfma_f32_16x16x32_bf16((a), (b), (c), 0, 0, 0)

__device__ __forceinline__ u16 f2bf(float f) {
    union { float f; unsigned u; } v; v.f = f;
    unsigned u = v.u;
    u += 0x7fffu + ((u >> 16) & 1u);   // RNE
    return (u16)(u >> 16);
}

// ------- K1: norm + fragment-major transpose + W-fragment convert ------------
// 256 blocks: b = bid>>6, 64-row tile nt. One read of x; writes xff + nrm.
// Blocks 0..31 additionally convert W -> Wf (one short8 chunk per thread).
__global__ __launch_bounds__(256) void k_prep(const float* __restrict__ x,
                                              const float* __restrict__ W,
                                              u16* __restrict__ xff,
                                              u16* __restrict__ Wf,
                                              float* __restrict__ nrm) {
    __shared__ float xs[256][65];     // 65 pad: conflict-free col reads
    __shared__ float part[4][64];
    __shared__ float rs_s[64];
    int bid = blockIdx.x;
    int b = bid >> 6, nt = bid & 63, n0 = nt << 6;
    int tid = threadIdx.x;

    // W fragment conversion (blocks 0..31; 8192 chunks total)
    if (bid < 32) {
        int q = (bid << 8) + tid;                 // chunk id 0..8191
        int lane = q & 63, kc = (q >> 6) & 7, ci = (q >> 9) & 3, wq = q >> 11;
        int row = (wq << 6) + (ci << 4) + (lane & 15);
        int col = (kc << 5) + ((lane >> 4) << 3);
        const float* wp = W + row * 256 + col;
        u16 tmp[8];
#pragma unroll
        for (int j = 0; j < 8; ++j) tmp[j] = f2bf(wp[j]);
        *(short8*)(Wf + ((size_t)q << 3)) = *(const short8*)tmp;
    }

    int rowg = tid >> 4, l16 = tid & 15;
    const float* xb = x + ((size_t)b << 20) + n0;
#pragma unroll
    for (int s = 0; s < 16; ++s) {
        int row = (s << 4) + rowg;                // c index
        float4 v = *(const float4*)(xb + (size_t)row * 4096 + (l16 << 2));
        xs[row][(l16 << 2) + 0] = v.x;
        xs[row][(l16 << 2) + 1] = v.y;
        xs[row][(l16 << 2) + 2] = v.z;
        xs[row][(l16 << 2) + 3] = v.w;
    }
    __syncthreads();
    int q2 = tid >> 6, nl = tid & 63;
    float ss = 0.f;
#pragma unroll 16
    for (int c = 0; c < 64; ++c) {
        float v = xs[(q2 << 6) + c][nl];
        ss += v * v;
    }
    part[q2][nl] = ss;
    __syncthreads();
    if (tid < 64) {
        float t = part[0][tid] + part[1][tid] + part[2][tid] + part[3][tid];
        float nr = sqrtf(t);
        nrm[(b << 12) + n0 + tid] = nr;
        rs_s[tid] = 1.0f / fmaxf(nr, 1e-8f);
    }
    __syncthreads();

    // xff write: fully coalesced. lane = (c8&3)*16 + (tl&15) == tid&63.
    u16* xo = xff + ((size_t)b << 20) + ((size_t)nt << 14);   // 32 chunks * 512 u16
    int lane = tid & 63;
#pragma unroll
    for (int s = 0; s < 8; ++s) {
        int w2 = (s << 2) + (tid >> 6);           // 0..31
        int tl = ((w2 & 3) << 4) + (tid & 15);    // local row 0..63
        int c8 = ((w2 >> 2) << 2) + ((tid >> 4) & 3);   // col-chunk 0..31
        float rsv = rs_s[tl];
        u16 tmp[8];
#pragma unroll
        for (int j = 0; j < 8; ++j)
            tmp[j] = f2bf(xs[(c8 << 3) + j][tl] * rsv);
        int chunk = ((tl >> 4) << 3) + (c8 >> 2); // rt*8 + kc
        *(short8*)(xo + (chunk << 9) + (lane << 3)) = *(const short8*)tmp;
    }
}

// ---- K2: T = nrm*(W xn) + bias, output fragment-major tbf -------------------
// 256 blocks: b = bid>>6, m-tile mt (64 m). 4 waves; wave wid owns c in
// [64wid, 64wid+64). All loads fragment-major coalesced; epilogue transposes
// through LDS and stores tbf coalesced.
__global__ __launch_bounds__(256) void k_tgemm(const u16* __restrict__ Wf,
                                               const u16* __restrict__ xff,
                                               const float* __restrict__ bias,
                                               const float* __restrict__ nrm,
                                               u16* __restrict__ tbf) {
    __shared__ u16 lds_t[256][72];    // 36 KB, rows 144B (16B-aligned)
    int bid = blockIdx.x;
    int b = bid >> 6, mt = bid & 63;
    const u16* xf_t = xff + ((size_t)b << 20) + ((size_t)mt << 14);
    int tid = threadIdx.x, wid = tid >> 6, lane = tid & 63, lg = lane >> 4, lr = lane & 15;

    f32x4 zero = {0.f, 0.f, 0.f, 0.f};
    f32x4 acc[4][4];
#pragma unroll
    for (int ci = 0; ci < 4; ++ci)
#pragma unroll
        for (int mj = 0; mj < 4; ++mj) acc[ci][mj] = zero;

#pragma unroll
    for (int kc = 0; kc < 8; ++kc) {
        short8 afr[4], bfr[4];
#pragma unroll
        for (int ci = 0; ci < 4; ++ci)
            afr[ci] = *(const short8*)(Wf + ((size_t)((((wid << 2) + ci) << 3) + kc) << 9)
                                       + (lane << 3));
#pragma unroll
        for (int mj = 0; mj < 4; ++mj)
            bfr[mj] = *(const short8*)(xf_t + ((size_t)(((mj << 3) + kc)) << 9)
                                       + (lane << 3));
#pragma unroll
        for (int ci = 0; ci < 4; ++ci)
#pragma unroll
            for (int mj = 0; mj < 4; ++mj)
                acc[ci][mj] = MFMA16(afr[ci], bfr[mj], acc[ci][mj]);
    }
    float nv[4];
#pragma unroll
    for (int mj = 0; mj < 4; ++mj)
        nv[mj] = nrm[(b << 12) + (mt << 6) + (mj << 4) + lr];
#pragma unroll
    for (int ci = 0; ci < 4; ++ci) {
#pragma unroll
        for (int r = 0; r < 4; ++r) {
            int c = (wid << 6) + (ci << 4) + (lg << 2) + r;
            float bv = bias[c];
#pragma unroll
            for (int mj = 0; mj < 4; ++mj)
                lds_t[c][(mj << 4) + lr] = f2bf(acc[ci][mj][r] * nv[mj] + bv);
        }
    }
    __syncthreads();
    u16* to = tbf + ((size_t)b << 20) + ((size_t)mt << 14);
#pragma unroll
    for (int s = 0; s < 8; ++s) {
        int w2 = (s << 2) + (tid >> 6);           // cq*8 + ci*2 + k2, 0..31
        int cq = w2 >> 3, ci2 = (w2 >> 1) & 3, k2 = w2 & 1;
        short8 v = *(const short8*)(&lds_t[(cq << 6) + (ci2 << 4) + lr][(k2 << 5) + (lg << 3)]);
        *(short8*)(to + (w2 << 9) + (lane << 3)) = v;
    }
}

// ---------------- K3: fused  O[:,ntile] = T * P^T  --------------------------
// 256 blocks (1/CU), 512 threads (8 waves). R6 skeleton, coalesced loads.
// Waves 0-3 producers: wave tc owns S cols [16tc,16tc+16); afrag persistent;
// streams its bfr chunks (1KB bursts) 1 tile ahead; writes swizzled lds_p.
// Waves 4-7 consumers: wave cq owns c rows [64cq,64cq+64); tbf chunks 1 tile
// ahead; P from lds_p. One lgkm-only barrier/iter; loads never drained.
__global__ __launch_bounds__(512) void k_fused(const u16* __restrict__ xff,
                                               const u16* __restrict__ tbf,
                                               float* __restrict__ out) {
    __shared__ __align__(16) u16 lds_p[2][4096];   // P dbuf, 64x64, swizzled

#define PBYTE(row, col) ((((row) << 7) + ((col) << 1)) ^ (((row) & 7) << 4))
#define BAR() do { asm volatile("s_waitcnt lgkmcnt(0)" ::: "memory");              \
    __builtin_amdgcn_sched_barrier(0); __builtin_amdgcn_s_barrier();               \
    __builtin_amdgcn_sched_barrier(0); } while (0)

    int bid = blockIdx.x;
    int xcd = bid & 7, grp = bid >> 3;
    int batch = xcd >> 1;
    int nt = grp + 32 * (xcd & 1);
    int n0 = nt << 6;

    const u16* xf_b = xff + ((size_t)batch << 20);
    const u16* tb_f = tbf + ((size_t)batch << 20);
    float* out_b = out + ((size_t)batch << 20);

    int tid = threadIdx.x;
    int wid = tid >> 6, lane = tid & 63, lg = lane >> 4, lr = lane & 15;
    f32x4 zero = {0.f, 0.f, 0.f, 0.f};

    if (wid < 4) {
        // ================= producer: S / P =================
        int tc = wid;
        // afrag: rows n0..n0+63, K=256 — from xff chunks (nt*4+rt)*8+kc
        short8 afrag[4][8];
#pragma unroll
        for (int rt = 0; rt < 4; ++rt)
#pragma unroll
            for (int kc = 0; kc < 8; ++kc)
                afrag[rt][kc] = *(const short8*)(xf_b
                    + ((size_t)((((nt << 2) + rt) << 3) + kc) << 9) + (lane << 3));
        // bfr stream: tile T chunk (T*4+tc)*8+kc -> base tc*8 chunks, stride 16384 u16/tile
        const u16* bstep = xf_b + ((size_t)(tc << 3) << 9) + (lane << 3);
        short8 bfrA[8], bfrB[8];
#pragma unroll
        for (int kc = 0; kc < 8; ++kc) bfrA[kc] = *(const short8*)(bstep + (kc << 9));
#pragma unroll
        for (int kc = 0; kc < 8; ++kc) bfrB[kc] = *(const short8*)(bstep + 16384 + (kc << 9));

#define SCOMP(BUF, PB)                                                                     \
    {                                                                                      \
        f32x4 sa0 = zero, sa1 = zero, sa2 = zero, sa3 = zero;                              \
        _Pragma("unroll")                                                                  \
        for (int kc = 0; kc < 8; ++kc) {                                                   \
            sa0 = MFMA16(afrag[0][kc], BUF[kc], sa0);                                      \
            sa1 = MFMA16(afrag[1][kc], BUF[kc], sa1);                                      \
            sa2 = MFMA16(afrag[2][kc], BUF[kc], sa2);                                      \
            sa3 = MFMA16(afrag[3][kc], BUF[kc], sa3);                                      \
        }                                                                                  \
        char* pd = (char*)&lds_p[PB][0];                                                   \
        int colw = (tc << 4) + lr;                                                         \
        _Pragma("unroll")                                                                  \
        for (int r = 0; r < 4; ++r) {                                                      \
            int rw = (lg << 2) + r;                                                        \
            float v0 = fmaxf(sa0[r], 0.f);                                                 \
            *(u16*)(pd + PBYTE(rw, colw)) = f2bf(v0 * v0);                                 \
            float v1 = fmaxf(sa1[r], 0.f);                                                 \
            *(u16*)(pd + PBYTE(rw + 16, colw)) = f2bf(v1 * v1);                            \
            float v2 = fmaxf(sa2[r], 0.f);                                                 \
            *(u16*)(pd + PBYTE(rw + 32, colw)) = f2bf(v2 * v2);                            \
            float v3 = fmaxf(sa3[r], 0.f);                                                 \
            *(u16*)(pd + PBYTE(rw + 48, colw)) = f2bf(v3 * v3);                            \
        }                                                                                  \
    }

        SCOMP(bfrA, 0);
        BAR();

#define SBODY(T, BC, BN)                                                                   \
    {                                                                                      \
        if ((T) <= 61) {                                                                   \
            _Pragma("unroll")                                                              \
            for (int kc = 0; kc < 8; ++kc)                                                 \
                BN[kc] = *(const short8*)(bstep + (size_t)((T) + 2) * 16384 + (kc << 9));  \
        }                                                                                  \
        if ((T) < 63) SCOMP(BC, ((T) + 1) & 1);                                            \
        BAR();                                                                             \
    }

        for (int t = 0; t < 64; t += 2) {
            SBODY(t, bfrB, bfrA);
            SBODY(t + 1, bfrA, bfrB);
        }
#undef SBODY
#undef SCOMP
    } else {
        // ================= consumer: O += T * P^T =================
        int cq = wid - 4;
        // tbf chunk (T*32 + cq*8 + ci*2 + k2)
        const u16* tstep = tb_f + ((size_t)(cq << 3) << 9) + (lane << 3);
        short8 tbcA[4][2], tbcB[4][2];
#pragma unroll
        for (int ci = 0; ci < 4; ++ci)
#pragma unroll
            for (int k2 = 0; k2 < 2; ++k2)
                tbcA[ci][k2] = *(const short8*)(tstep + (((ci << 1) + k2) << 9));

        f32x4 oacc[4][4];
#pragma unroll
        for (int ci = 0; ci < 4; ++ci)
#pragma unroll
            for (int nj = 0; nj < 4; ++nj) oacc[ci][nj] = zero;
        BAR();

#define OBODY(T, TC, TN)                                                                   \
    {                                                                                      \
        if ((T) <= 62) {                                                                   \
            _Pragma("unroll")                                                              \
            for (int ci = 0; ci < 4; ++ci) {                                               \
                _Pragma("unroll")                                                          \
                for (int k2 = 0; k2 < 2; ++k2)                                             \
                    TN[ci][k2] = *(const short8*)(tstep + (size_t)((T) + 1) * 16384        \
                                                  + (((ci << 1) + k2) << 9));             \
            }                                                                              \
        }                                                                                  \
        char* pc = (char*)&lds_p[(T) & 1][0];                                              \
        short8 pfr[4][2];                                                                  \
        _Pragma("unroll")                                                                  \
        for (int nj = 0; nj < 4; ++nj) {                                                   \
            _Pragma("unroll")                                                              \
            for (int k2 = 0; k2 < 2; ++k2)                                                 \
                pfr[nj][k2] = *(const short8*)(pc + PBYTE((nj << 4) + lr,                  \
                                                          (k2 << 5) + (lg << 3)));        \
        }                                                                                  \
        _Pragma("unroll")                                                                  \
        for (int ci = 0; ci < 4; ++ci) {                                                   \
            _Pragma("unroll")                                                              \
            for (int nj = 0; nj < 4; ++nj) {                                               \
                oacc[ci][nj] = MFMA16(TC[ci][0], pfr[nj][0], oacc[ci][nj]);                \
                oacc[ci][nj] = MFMA16(TC[ci][1], pfr[nj][1], oacc[ci][nj]);                \
            }                                                                              \
        }                                                                                  \
        BAR();                                                                             \
    }

        for (int t = 0; t < 64; t += 2) {
            OBODY(t, tbcA, tbcB);
            OBODY(t + 1, tbcB, tbcA);
        }
#undef OBODY

        // epilogue: write O fp32
#pragma unroll
        for (int ci = 0; ci < 4; ++ci) {
            int c = (cq << 6) + (ci << 4) + (lg << 2);
#pragma unroll
            for (int nj = 0; nj < 4; ++nj) {
                int n = n0 + (nj << 4) + lr;
                float* op = out_b + (size_t)c * 4096 + n;
#pragma unroll
                for (int r = 0; r < 4; ++r) op[(size_t)r * 4096] = oacc[ci][nj][r];
            }
        }
    }
#undef PBYTE
#undef BAR
}

extern "C" void kernel_launch(void* const* d_in, const int* in_sizes, int n_in,
                              void* d_out, int out_size, void* d_ws, size_t ws_size,
                              hipStream_t stream) {
    const float* x = (const float*)d_in[0];     // (4,256,16,16,16) fp32
    const float* W = (const float*)d_in[1];     // (256,256) fp32
    const float* bias = (const float*)d_in[2];  // (256,) fp32
    float* out = (float*)d_out;

    char* ws = (char*)d_ws;
    u16* xff = (u16*)ws;                                   // 8 MiB: xn fragment-major
    u16* tbf = (u16*)(ws + ((size_t)8 << 20));             // 8 MiB: T fragment-major
    u16* Wf = (u16*)(ws + ((size_t)16 << 20));             // 128 KiB: W fragment-major
    float* nrm = (float*)(ws + ((size_t)16 << 20) + (192u << 10));  // 64 KiB

    hipLaunchKernelGGL(k_prep, dim3(256), dim3(256), 0, stream, x, W, xff, Wf, nrm);
    hipLaunchKernelGGL(k_tgemm, dim3(256), dim3(256), 0, stream, Wf, xff, bias, nrm, tbf);
    hipLaunchKernelGGL(k_fused, dim3(256), dim3(512), 0, stream, xff, tbf, out);
}

// Round 9
// 84.128 us; speedup vs baseline: 3.1996x; 1.0193x over previous
//
#include <hip/hip_runtime.h>
#include <hip/hip_bf16.h>

// Problem: B=4, C=256, N=4096 (16^3).
// out[b,c,n] = sum_m relu(cos(x_n,x_m))^2 * (W x + b)[c,m]
// xn = x/||x|| (bf16) -> S = xn^T xn, P = relu(S)^2,
// T[c,m] = nrm[m]*(W xn)[c,m] + b[c],  out = T * P^T.
//
// r8: fragment-major layouts (xff/Wf/tbf) -> every k_fused in-loop load is
// base + lane*16B (coalesced). r9: 4-slot P-ring, one barrier per 2 tiles,
// setprio around MFMA clusters (T5 regime: producer/consumer role split).

typedef unsigned short u16;
typedef __attribute__((ext_vector_type(8))) short short8;   // 8 bf16 = 4 VGPRs
typedef __attribute__((ext_vector_type(4))) float f32x4;

#define MFMA16(a, b, c) __builtin_amdgcn_mfma_f32_16x16x32_bf16((a), (b), (c), 0, 0, 0)

__device__ __forceinline__ u16 f2bf(float f) {
    union { float f; unsigned u; } v; v.f = f;
    unsigned u = v.u;
    u += 0x7fffu + ((u >> 16) & 1u);   // RNE
    return (u16)(u >> 16);
}

// ------- K1: norm + fragment-major transpose + W-fragment convert ------------
__global__ __launch_bounds__(256) void k_prep(const float* __restrict__ x,
                                              const float* __restrict__ W,
                                              u16* __restrict__ xff,
                                              u16* __restrict__ Wf,
                                              float* __restrict__ nrm) {
    __shared__ float xs[256][65];     // 65 pad: conflict-free col reads
    __shared__ float part[4][64];
    __shared__ float rs_s[64];
    int bid = blockIdx.x;
    int b = bid >> 6, nt = bid & 63, n0 = nt << 6;
    int tid = threadIdx.x;

    if (bid < 32) {       // W fragment conversion (8192 chunks total)
        int q = (bid << 8) + tid;
        int lane = q & 63, kc = (q >> 6) & 7, ci = (q >> 9) & 3, wq = q >> 11;
        int row = (wq << 6) + (ci << 4) + (lane & 15);
        int col = (kc << 5) + ((lane >> 4) << 3);
        const float* wp = W + row * 256 + col;
        u16 tmp[8];
#pragma unroll
        for (int j = 0; j < 8; ++j) tmp[j] = f2bf(wp[j]);
        *(short8*)(Wf + ((size_t)q << 3)) = *(const short8*)tmp;
    }

    int rowg = tid >> 4, l16 = tid & 15;
    const float* xb = x + ((size_t)b << 20) + n0;
#pragma unroll
    for (int s = 0; s < 16; ++s) {
        int row = (s << 4) + rowg;                // c index
        float4 v = *(const float4*)(xb + (size_t)row * 4096 + (l16 << 2));
        xs[row][(l16 << 2) + 0] = v.x;
        xs[row][(l16 << 2) + 1] = v.y;
        xs[row][(l16 << 2) + 2] = v.z;
        xs[row][(l16 << 2) + 3] = v.w;
    }
    __syncthreads();
    int q2 = tid >> 6, nl = tid & 63;
    float ss = 0.f;
#pragma unroll 16
    for (int c = 0; c < 64; ++c) {
        float v = xs[(q2 << 6) + c][nl];
        ss += v * v;
    }
    part[q2][nl] = ss;
    __syncthreads();
    if (tid < 64) {
        float t = part[0][tid] + part[1][tid] + part[2][tid] + part[3][tid];
        float nr = sqrtf(t);
        nrm[(b << 12) + n0 + tid] = nr;
        rs_s[tid] = 1.0f / fmaxf(nr, 1e-8f);
    }
    __syncthreads();

    u16* xo = xff + ((size_t)b << 20) + ((size_t)nt << 14);
    int lane = tid & 63;
#pragma unroll
    for (int s = 0; s < 8; ++s) {
        int w2 = (s << 2) + (tid >> 6);           // 0..31
        int tl = ((w2 & 3) << 4) + (tid & 15);    // local row 0..63
        int c8 = ((w2 >> 2) << 2) + ((tid >> 4) & 3);   // col-chunk 0..31
        float rsv = rs_s[tl];
        u16 tmp[8];
#pragma unroll
        for (int j = 0; j < 8; ++j)
            tmp[j] = f2bf(xs[(c8 << 3) + j][tl] * rsv);
        int chunk = ((tl >> 4) << 3) + (c8 >> 2); // rt*8 + kc
        *(short8*)(xo + (chunk << 9) + (lane << 3)) = *(const short8*)tmp;
    }
}

// ---- K2: T = nrm*(W xn) + bias, output fragment-major tbf -------------------
__global__ __launch_bounds__(256) void k_tgemm(const u16* __restrict__ Wf,
                                               const u16* __restrict__ xff,
                                               const float* __restrict__ bias,
                                               const float* __restrict__ nrm,
                                               u16* __restrict__ tbf) {
    __shared__ u16 lds_t[256][72];
    int bid = blockIdx.x;
    int b = bid >> 6, mt = bid & 63;
    const u16* xf_t = xff + ((size_t)b << 20) + ((size_t)mt << 14);
    int tid = threadIdx.x, wid = tid >> 6, lane = tid & 63, lg = lane >> 4, lr = lane & 15;

    f32x4 zero = {0.f, 0.f, 0.f, 0.f};
    f32x4 acc[4][4];
#pragma unroll
    for (int ci = 0; ci < 4; ++ci)
#pragma unroll
        for (int mj = 0; mj < 4; ++mj) acc[ci][mj] = zero;

#pragma unroll
    for (int kc = 0; kc < 8; ++kc) {
        short8 afr[4], bfr[4];
#pragma unroll
        for (int ci = 0; ci < 4; ++ci)
            afr[ci] = *(const short8*)(Wf + ((size_t)((((wid << 2) + ci) << 3) + kc) << 9)
                                       + (lane << 3));
#pragma unroll
        for (int mj = 0; mj < 4; ++mj)
            bfr[mj] = *(const short8*)(xf_t + ((size_t)(((mj << 3) + kc)) << 9)
                                       + (lane << 3));
#pragma unroll
        for (int ci = 0; ci < 4; ++ci)
#pragma unroll
            for (int mj = 0; mj < 4; ++mj)
                acc[ci][mj] = MFMA16(afr[ci], bfr[mj], acc[ci][mj]);
    }
    float nv[4];
#pragma unroll
    for (int mj = 0; mj < 4; ++mj)
        nv[mj] = nrm[(b << 12) + (mt << 6) + (mj << 4) + lr];
#pragma unroll
    for (int ci = 0; ci < 4; ++ci) {
#pragma unroll
        for (int r = 0; r < 4; ++r) {
            int c = (wid << 6) + (ci << 4) + (lg << 2) + r;
            float bv = bias[c];
#pragma unroll
            for (int mj = 0; mj < 4; ++mj)
                lds_t[c][(mj << 4) + lr] = f2bf(acc[ci][mj][r] * nv[mj] + bv);
        }
    }
    __syncthreads();
    u16* to = tbf + ((size_t)b << 20) + ((size_t)mt << 14);
#pragma unroll
    for (int s = 0; s < 8; ++s) {
        int w2 = (s << 2) + (tid >> 6);
        int cq = w2 >> 3, ci2 = (w2 >> 1) & 3, k2 = w2 & 1;
        short8 v = *(const short8*)(&lds_t[(cq << 6) + (ci2 << 4) + lr][(k2 << 5) + (lg << 3)]);
        *(short8*)(to + (w2 << 9) + (lane << 3)) = v;
    }
}

// ---------------- K3: fused  O[:,ntile] = T * P^T  --------------------------
// 256 blocks (1/CU), 512 threads (8 waves), producer/consumer split.
// r9 cadence: 4-slot swizzled P-ring (slot = tile&3, 8KB each); ONE lgkm-only
// barrier per 2 tiles. Phase p: consumers eat tiles {2p,2p+1} (slots disjoint
// from producer's {2p+2,2p+3}); reg sets consume-then-reload (A=even tile,
// B=odd), so in-flight register state is unchanged vs r8 (we sit at the
// 244/256 VGPR+AGPR budget). setprio(1) wraps each MFMA cluster (T5).
__global__ __launch_bounds__(512) void k_fused(const u16* __restrict__ xff,
                                               const u16* __restrict__ tbf,
                                               float* __restrict__ out) {
    __shared__ __align__(16) u16 lds_p[4][4096];   // P ring, 4 x 8KB, swizzled

#define PBYTE(row, col) ((((row) << 7) + ((col) << 1)) ^ (((row) & 7) << 4))
#define BAR() do { asm volatile("s_waitcnt lgkmcnt(0)" ::: "memory");              \
    __builtin_amdgcn_sched_barrier(0); __builtin_amdgcn_s_barrier();               \
    __builtin_amdgcn_sched_barrier(0); } while (0)

    int bid = blockIdx.x;
    int xcd = bid & 7, grp = bid >> 3;
    int batch = xcd >> 1;
    int nt = grp + 32 * (xcd & 1);
    int n0 = nt << 6;

    const u16* xf_b = xff + ((size_t)batch << 20);
    const u16* tb_f = tbf + ((size_t)batch << 20);
    float* out_b = out + ((size_t)batch << 20);

    int tid = threadIdx.x;
    int wid = tid >> 6, lane = tid & 63, lg = lane >> 4, lr = lane & 15;
    f32x4 zero = {0.f, 0.f, 0.f, 0.f};

    if (wid < 4) {
        // ================= producer: S / P =================
        int tc = wid;
        short8 afrag[4][8];
#pragma unroll
        for (int rt = 0; rt < 4; ++rt)
#pragma unroll
            for (int kc = 0; kc < 8; ++kc)
                afrag[rt][kc] = *(const short8*)(xf_b
                    + ((size_t)((((nt << 2) + rt) << 3) + kc) << 9) + (lane << 3));
        const u16* bstep = xf_b + ((size_t)(tc << 3) << 9) + (lane << 3);
        short8 bfrA[8], bfrB[8];
#pragma unroll
        for (int kc = 0; kc < 8; ++kc) bfrA[kc] = *(const short8*)(bstep + (kc << 9));
#pragma unroll
        for (int kc = 0; kc < 8; ++kc) bfrB[kc] = *(const short8*)(bstep + 16384 + (kc << 9));

#define SCOMP(BUF, SLOT)                                                                   \
    {                                                                                      \
        f32x4 sa0 = zero, sa1 = zero, sa2 = zero, sa3 = zero;                              \
        __builtin_amdgcn_s_setprio(1);                                                     \
        _Pragma("unroll")                                                                  \
        for (int kc = 0; kc < 8; ++kc) {                                                   \
            sa0 = MFMA16(afrag[0][kc], BUF[kc], sa0);                                      \
            sa1 = MFMA16(afrag[1][kc], BUF[kc], sa1);                                      \
            sa2 = MFMA16(afrag[2][kc], BUF[kc], sa2);                                      \
            sa3 = MFMA16(afrag[3][kc], BUF[kc], sa3);                                      \
        }                                                                                  \
        __builtin_amdgcn_s_setprio(0);                                                     \
        char* pd = (char*)&lds_p[0][0] + ((SLOT) << 13);                                   \
        int colw = (tc << 4) + lr;                                                         \
        _Pragma("unroll")                                                                  \
        for (int r = 0; r < 4; ++r) {                                                      \
            int rw = (lg << 2) + r;                                                        \
            float v0 = fmaxf(sa0[r], 0.f);                                                 \
            *(u16*)(pd + PBYTE(rw, colw)) = f2bf(v0 * v0);                                 \
            float v1 = fmaxf(sa1[r], 0.f);                                                 \
            *(u16*)(pd + PBYTE(rw + 16, colw)) = f2bf(v1 * v1);                            \
            float v2 = fmaxf(sa2[r], 0.f);                                                 \
            *(u16*)(pd + PBYTE(rw + 32, colw)) = f2bf(v2 * v2);                            \
            float v3 = fmaxf(sa3[r], 0.f);                                                 \
            *(u16*)(pd + PBYTE(rw + 48, colw)) = f2bf(v3 * v3);                            \
        }                                                                                  \
    }

        // prologue: tiles 0,1 -> slots 0,1; reload sets with tiles 2,3
        SCOMP(bfrA, 0);
#pragma unroll
        for (int kc = 0; kc < 8; ++kc)
            bfrA[kc] = *(const short8*)(bstep + 2 * 16384 + (kc << 9));
        SCOMP(bfrB, 1);
#pragma unroll
        for (int kc = 0; kc < 8; ++kc)
            bfrB[kc] = *(const short8*)(bstep + 3 * 16384 + (kc << 9));
        BAR();

        // phases: produce tiles {pt, pt+1}, reload {pt+2, pt+3}
        for (int pt = 2; pt <= 64; pt += 2) {
            if (pt <= 63) SCOMP(bfrA, (pt & 3));
            if (pt + 2 <= 63) {
#pragma unroll
                for (int kc = 0; kc < 8; ++kc)
                    bfrA[kc] = *(const short8*)(bstep + (size_t)(pt + 2) * 16384 + (kc << 9));
            }
            if (pt + 1 <= 63) SCOMP(bfrB, ((pt + 1) & 3));
            if (pt + 3 <= 63) {
#pragma unroll
                for (int kc = 0; kc < 8; ++kc)
                    bfrB[kc] = *(const short8*)(bstep + (size_t)(pt + 3) * 16384 + (kc << 9));
            }
            BAR();
        }
#undef SCOMP
    } else {
        // ================= consumer: O += T * P^T =================
        int cq = wid - 4;
        const u16* tstep = tb_f + ((size_t)(cq << 3) << 9) + (lane << 3);
        short8 tbcA[4][2], tbcB[4][2];
#pragma unroll
        for (int ci = 0; ci < 4; ++ci)
#pragma unroll
            for (int k2 = 0; k2 < 2; ++k2) {
                tbcA[ci][k2] = *(const short8*)(tstep + (((ci << 1) + k2) << 9));
                tbcB[ci][k2] = *(const short8*)(tstep + 16384 + (((ci << 1) + k2) << 9));
            }

        f32x4 oacc[4][4];
#pragma unroll
        for (int ci = 0; ci < 4; ++ci)
#pragma unroll
            for (int nj = 0; nj < 4; ++nj) oacc[ci][nj] = zero;
        BAR();

#define OEAT(TC, SLOT)                                                                     \
    {                                                                                      \
        char* pc = (char*)&lds_p[0][0] + ((SLOT) << 13);                                   \
        short8 pfr[4][2];                                                                  \
        _Pragma("unroll")                                                                  \
        for (int nj = 0; nj < 4; ++nj) {                                                   \
            _Pragma("unroll")                                                              \
            for (int k2 = 0; k2 < 2; ++k2)                                                 \
                pfr[nj][k2] = *(const short8*)(pc + PBYTE((nj << 4) + lr,                  \
                                                          (k2 << 5) + (lg << 3)));        \
        }                                                                                  \
        __builtin_amdgcn_s_setprio(1);                                                     \
        _Pragma("unroll")                                                                  \
        for (int ci = 0; ci < 4; ++ci) {                                                   \
            _Pragma("unroll")                                                              \
            for (int nj = 0; nj < 4; ++nj) {                                               \
                oacc[ci][nj] = MFMA16(TC[ci][0], pfr[nj][0], oacc[ci][nj]);                \
                oacc[ci][nj] = MFMA16(TC[ci][1], pfr[nj][1], oacc[ci][nj]);                \
            }                                                                              \
        }                                                                                  \
        __builtin_amdgcn_s_setprio(0);                                                     \
    }

        // phases: eat tiles {ct, ct+1}, reload {ct+2, ct+3}
        for (int ct = 0; ct <= 62; ct += 2) {
            OEAT(tbcA, (ct & 3));
            if (ct + 2 <= 63) {
#pragma unroll
                for (int ci = 0; ci < 4; ++ci)
#pragma unroll
                    for (int k2 = 0; k2 < 2; ++k2)
                        tbcA[ci][k2] = *(const short8*)(tstep + (size_t)(ct + 2) * 16384
                                                        + (((ci << 1) + k2) << 9));
            }
            OEAT(tbcB, ((ct + 1) & 3));
            if (ct + 3 <= 63) {
#pragma unroll
                for (int ci = 0; ci < 4; ++ci)
#pragma unroll
                    for (int k2 = 0; k2 < 2; ++k2)
                        tbcB[ci][k2] = *(const short8*)(tstep + (size_t)(ct + 3) * 16384
                                                        + (((ci << 1) + k2) << 9));
            }
            BAR();
        }
#undef OEAT

        // epilogue: write O fp32
#pragma unroll
        for (int ci = 0; ci < 4; ++ci) {
            int c = (cq << 6) + (ci << 4) + (lg << 2);
#pragma unroll
            for (int nj = 0; nj < 4; ++nj) {
                int n = n0 + (nj << 4) + lr;
                float* op = out_b + (size_t)c * 4096 + n;
#pragma unroll
                for (int r = 0; r < 4; ++r) op[(size_t)r * 4096] = oacc[ci][nj][r];
            }
        }
    }
#undef PBYTE
#undef BAR
}

extern "C" void kernel_launch(void* const* d_in, const int* in_sizes, int n_in,
                              void* d_out, int out_size, void* d_ws, size_t ws_size,
                              hipStream_t stream) {
    const float* x = (const float*)d_in[0];     // (4,256,16,16,16) fp32
    const float* W = (const float*)d_in[1];     // (256,256) fp32
    const float* bias = (const float*)d_in[2];  // (256,) fp32
    float* out = (float*)d_out;

    char* ws = (char*)d_ws;
    u16* xff = (u16*)ws;                                   // 8 MiB: xn fragment-major
    u16* tbf = (u16*)(ws + ((size_t)8 << 20));             // 8 MiB: T fragment-major
    u16* Wf = (u16*)(ws + ((size_t)16 << 20));             // 128 KiB: W fragment-major
    float* nrm = (float*)(ws + ((size_t)16 << 20) + (192u << 10));  // 64 KiB

    hipLaunchKernelGGL(k_prep, dim3(256), dim3(256), 0, stream, x, W, xff, Wf, nrm);
    hipLaunchKernelGGL(k_tgemm, dim3(256), dim3(256), 0, stream, Wf, xff, bias, nrm, tbf);
    hipLaunchKernelGGL(k_fused, dim3(256), dim3(512), 0, stream, xff, tbf, out);
}

// Round 10
// 77.110 us; speedup vs baseline: 3.4908x; 1.0910x over previous
//
#include <hip/hip_runtime.h>
#include <hip/hip_bf16.h>

// Problem: B=4, C=256, N=4096 (16^3).
// out[b,c,n] = sum_m relu(cos(x_n,x_m))^2 * (W x + b)[c,m]
// xn = x/||x|| (bf16) -> S = xn^T xn, P = relu(S)^2,
// T[c,m] = nrm[m]*(W xn)[c,m] + b[c],  out = T * P^T.
//
// r8: fragment-major layouts (xff/Wf/tbf) -> every k_fused in-loop load is
// base + lane*16B (coalesced). r9: 4-slot P-ring, 2-tile phases, setprio.
// r10: cvt_pk P-packing, uniform-base += pointer addressing (imm offsets),
// full phase-pair unroll (compile-time ring slots), both-slot pfr prefetch.

typedef unsigned short u16;
typedef __attribute__((ext_vector_type(8))) short short8;   // 8 bf16 = 4 VGPRs
typedef __attribute__((ext_vector_type(4))) float f32x4;

#define MFMA16(a, b, c) __builtin_amdgcn_mfma_f32_16x16x32_bf16((a), (b), (c), 0, 0, 0)

__device__ __forceinline__ u16 f2bf(float f) {
    union { float f; unsigned u; } v; v.f = f;
    unsigned u = v.u;
    u += 0x7fffu + ((u >> 16) & 1u);   // RNE
    return (u16)(u >> 16);
}

__device__ __forceinline__ unsigned cvtpk(float lo, float hi) {   // 2x f32 -> packed bf16 (RNE)
    unsigned r;
    asm("v_cvt_pk_bf16_f32 %0, %1, %2" : "=v"(r) : "v"(lo), "v"(hi));
    return r;
}

// ------- K1: norm + fragment-major transpose + W-fragment convert ------------
__global__ __launch_bounds__(256) void k_prep(const float* __restrict__ x,
                                              const float* __restrict__ W,
                                              u16* __restrict__ xff,
                                              u16* __restrict__ Wf,
                                              float* __restrict__ nrm) {
    __shared__ float xs[256][65];     // 65 pad: conflict-free col reads
    __shared__ float part[4][64];
    __shared__ float rs_s[64];
    int bid = blockIdx.x;
    int b = bid >> 6, nt = bid & 63, n0 = nt << 6;
    int tid = threadIdx.x;

    if (bid < 32) {       // W fragment conversion (8192 chunks total)
        int q = (bid << 8) + tid;
        int lane = q & 63, kc = (q >> 6) & 7, ci = (q >> 9) & 3, wq = q >> 11;
        int row = (wq << 6) + (ci << 4) + (lane & 15);
        int col = (kc << 5) + ((lane >> 4) << 3);
        const float* wp = W + row * 256 + col;
        u16 tmp[8];
#pragma unroll
        for (int j = 0; j < 8; ++j) tmp[j] = f2bf(wp[j]);
        *(short8*)(Wf + ((size_t)q << 3)) = *(const short8*)tmp;
    }

    int rowg = tid >> 4, l16 = tid & 15;
    const float* xb = x + ((size_t)b << 20) + n0;
#pragma unroll
    for (int s = 0; s < 16; ++s) {
        int row = (s << 4) + rowg;                // c index
        float4 v = *(const float4*)(xb + (size_t)row * 4096 + (l16 << 2));
        xs[row][(l16 << 2) + 0] = v.x;
        xs[row][(l16 << 2) + 1] = v.y;
        xs[row][(l16 << 2) + 2] = v.z;
        xs[row][(l16 << 2) + 3] = v.w;
    }
    __syncthreads();
    int q2 = tid >> 6, nl = tid & 63;
    float ss = 0.f;
#pragma unroll 16
    for (int c = 0; c < 64; ++c) {
        float v = xs[(q2 << 6) + c][nl];
        ss += v * v;
    }
    part[q2][nl] = ss;
    __syncthreads();
    if (tid < 64) {
        float t = part[0][tid] + part[1][tid] + part[2][tid] + part[3][tid];
        float nr = sqrtf(t);
        nrm[(b << 12) + n0 + tid] = nr;
        rs_s[tid] = 1.0f / fmaxf(nr, 1e-8f);
    }
    __syncthreads();

    u16* xo = xff + ((size_t)b << 20) + ((size_t)nt << 14);
    int lane = tid & 63;
#pragma unroll
    for (int s = 0; s < 8; ++s) {
        int w2 = (s << 2) + (tid >> 6);           // 0..31
        int tl = ((w2 & 3) << 4) + (tid & 15);    // local row 0..63
        int c8 = ((w2 >> 2) << 2) + ((tid >> 4) & 3);   // col-chunk 0..31
        float rsv = rs_s[tl];
        u16 tmp[8];
#pragma unroll
        for (int j = 0; j < 8; ++j)
            tmp[j] = f2bf(xs[(c8 << 3) + j][tl] * rsv);
        int chunk = ((tl >> 4) << 3) + (c8 >> 2); // rt*8 + kc
        *(short8*)(xo + (chunk << 9) + (lane << 3)) = *(const short8*)tmp;
    }
}

// ---- K2: T = nrm*(W xn) + bias, output fragment-major tbf -------------------
__global__ __launch_bounds__(256) void k_tgemm(const u16* __restrict__ Wf,
                                               const u16* __restrict__ xff,
                                               const float* __restrict__ bias,
                                               const float* __restrict__ nrm,
                                               u16* __restrict__ tbf) {
    __shared__ u16 lds_t[256][72];
    int bid = blockIdx.x;
    int b = bid >> 6, mt = bid & 63;
    const u16* xf_t = xff + ((size_t)b << 20) + ((size_t)mt << 14);
    int tid = threadIdx.x, wid = tid >> 6, lane = tid & 63, lg = lane >> 4, lr = lane & 15;

    f32x4 zero = {0.f, 0.f, 0.f, 0.f};
    f32x4 acc[4][4];
#pragma unroll
    for (int ci = 0; ci < 4; ++ci)
#pragma unroll
        for (int mj = 0; mj < 4; ++mj) acc[ci][mj] = zero;

#pragma unroll
    for (int kc = 0; kc < 8; ++kc) {
        short8 afr[4], bfr[4];
#pragma unroll
        for (int ci = 0; ci < 4; ++ci)
            afr[ci] = *(const short8*)(Wf + ((size_t)((((wid << 2) + ci) << 3) + kc) << 9)
                                       + (lane << 3));
#pragma unroll
        for (int mj = 0; mj < 4; ++mj)
            bfr[mj] = *(const short8*)(xf_t + ((size_t)(((mj << 3) + kc)) << 9)
                                       + (lane << 3));
#pragma unroll
        for (int ci = 0; ci < 4; ++ci)
#pragma unroll
            for (int mj = 0; mj < 4; ++mj)
                acc[ci][mj] = MFMA16(afr[ci], bfr[mj], acc[ci][mj]);
    }
    float nv[4];
#pragma unroll
    for (int mj = 0; mj < 4; ++mj)
        nv[mj] = nrm[(b << 12) + (mt << 6) + (mj << 4) + lr];
#pragma unroll
    for (int ci = 0; ci < 4; ++ci) {
#pragma unroll
        for (int r = 0; r < 4; ++r) {
            int c = (wid << 6) + (ci << 4) + (lg << 2) + r;
            float bv = bias[c];
#pragma unroll
            for (int mj = 0; mj < 4; ++mj)
                lds_t[c][(mj << 4) + lr] = f2bf(acc[ci][mj][r] * nv[mj] + bv);
        }
    }
    __syncthreads();
    u16* to = tbf + ((size_t)b << 20) + ((size_t)mt << 14);
#pragma unroll
    for (int s = 0; s < 8; ++s) {
        int w2 = (s << 2) + (tid >> 6);
        int cq = w2 >> 3, ci2 = (w2 >> 1) & 3, k2 = w2 & 1;
        short8 v = *(const short8*)(&lds_t[(cq << 6) + (ci2 << 4) + lr][(k2 << 5) + (lg << 3)]);
        *(short8*)(to + (w2 << 9) + (lane << 3)) = v;
    }
}

// ---------------- K3: fused  O[:,ntile] = T * P^T  --------------------------
// 256 blocks (1/CU), 512 threads (8 waves), producer/consumer split.
// 4-slot swizzled P-ring; 2-tile phases, phase-PAIRS unrolled so ring slots
// are compile-time; wave-uniform base pointers advanced += 32768/phase so all
// in-loop global offsets are immediates; cvt_pk P-pack; consumers prefetch
// both slots' pfr at phase start. Ring/barrier schedule identical to r9.
__global__ __launch_bounds__(512) void k_fused(const u16* __restrict__ xff,
                                               const u16* __restrict__ tbf,
                                               float* __restrict__ out) {
    __shared__ __align__(16) u16 lds_p[4][4096];   // P ring, 4 x 8KB, swizzled

#define PBYTE(row, col) ((((row) << 7) + ((col) << 1)) ^ (((row) & 7) << 4))
#define BAR() do { asm volatile("s_waitcnt lgkmcnt(0)" ::: "memory");              \
    __builtin_amdgcn_sched_barrier(0); __builtin_amdgcn_s_barrier();               \
    __builtin_amdgcn_sched_barrier(0); } while (0)

    int bid = blockIdx.x;
    int xcd = bid & 7, grp = bid >> 3;
    int batch = xcd >> 1;
    int nt = grp + 32 * (xcd & 1);
    int n0 = nt << 6;

    const u16* xf_b = xff + ((size_t)batch << 20);
    const u16* tb_f = tbf + ((size_t)batch << 20);
    float* out_b = out + ((size_t)batch << 20);

    int tid = threadIdx.x;
    int wid = tid >> 6, lane = tid & 63, lg = lane >> 4, lr = lane & 15;
    int lane8 = lane << 3;            // per-lane element offset (16B/lane)
    f32x4 zero = {0.f, 0.f, 0.f, 0.f};
    char* pbase = (char*)&lds_p[0][0];

    if (wid < 4) {
        // ================= producer: S / P =================
        int tc = wid;
        int colw = (tc << 4) + lr;
        short8 afrag[4][8];
#pragma unroll
        for (int rt = 0; rt < 4; ++rt)
#pragma unroll
            for (int kc = 0; kc < 8; ++kc)
                afrag[rt][kc] = *(const short8*)(xf_b
                    + ((size_t)((((nt << 2) + rt) << 3) + kc) << 9) + lane8);
        // wave-uniform chunk base (lane offset added at use); 16384 u16 per tile
        const u16* bb = xf_b + ((size_t)(tc << 3) << 9);
        short8 bfrA[8], bfrB[8];

#define RLDB(BUF, OFF)                                                                     \
        { _Pragma("unroll")                                                                \
          for (int kc = 0; kc < 8; ++kc)                                                   \
              BUF[kc] = *(const short8*)(bb + (OFF) + (kc << 9) + lane8); }

#define SCOMP(BUF, SLOT)                                                                   \
    {                                                                                      \
        f32x4 sac[4];                                                                      \
        _Pragma("unroll") for (int c = 0; c < 4; ++c) sac[c] = zero;                       \
        __builtin_amdgcn_s_setprio(1);                                                     \
        _Pragma("unroll")                                                                  \
        for (int kc = 0; kc < 8; ++kc) {                                                   \
            sac[0] = MFMA16(afrag[0][kc], BUF[kc], sac[0]);                                \
            sac[1] = MFMA16(afrag[1][kc], BUF[kc], sac[1]);                                \
            sac[2] = MFMA16(afrag[2][kc], BUF[kc], sac[2]);                                \
            sac[3] = MFMA16(afrag[3][kc], BUF[kc], sac[3]);                                \
        }                                                                                  \
        __builtin_amdgcn_s_setprio(0);                                                     \
        char* pd = pbase + ((SLOT) << 13);                                                 \
        _Pragma("unroll")                                                                  \
        for (int c = 0; c < 4; ++c) {                                                      \
            float q0 = fmaxf(sac[c][0], 0.f); q0 *= q0;                                    \
            float q1 = fmaxf(sac[c][1], 0.f); q1 *= q1;                                    \
            float q2 = fmaxf(sac[c][2], 0.f); q2 *= q2;                                    \
            float q3 = fmaxf(sac[c][3], 0.f); q3 *= q3;                                    \
            unsigned d01 = cvtpk(q0, q1);                                                  \
            unsigned d23 = cvtpk(q2, q3);                                                  \
            int rw = (lg << 2) + (c << 4);                                                 \
            *(u16*)(pd + PBYTE(rw, colw)) = (u16)d01;                                      \
            *(u16*)(pd + PBYTE(rw + 1, colw)) = (u16)(d01 >> 16);                          \
            *(u16*)(pd + PBYTE(rw + 2, colw)) = (u16)d23;                                  \
            *(u16*)(pd + PBYTE(rw + 3, colw)) = (u16)(d23 >> 16);                          \
        }                                                                                  \
    }

        // prologue: tiles 0,1 -> slots 0,1; reload tiles 2,3
        RLDB(bfrA, 0);
        RLDB(bfrB, 16384);
        bb += 32768;                    // -> tile 2
        SCOMP(bfrA, 0);
        RLDB(bfrA, 0);                  // tile 2
        SCOMP(bfrB, 1);
        RLDB(bfrB, 16384);              // tile 3
        bb += 32768;                    // -> tile 4
        BAR();

        // main: pp covers pt=4pp+2 (slots 2,3) and pt=4pp+4 (slots 0,1)
        for (int pp = 0; pp < 15; ++pp) {
            SCOMP(bfrA, 2);
            RLDB(bfrA, 0);
            SCOMP(bfrB, 3);
            RLDB(bfrB, 16384);
            bb += 32768;
            BAR();
            SCOMP(bfrA, 0);
            RLDB(bfrA, 0);
            SCOMP(bfrB, 1);
            RLDB(bfrB, 16384);
            bb += 32768;
            BAR();
        }
        // tail: pt=62 -> tiles 62,63 (slots 2,3), no reloads
        SCOMP(bfrA, 2);
        SCOMP(bfrB, 3);
        BAR();
        // pt=64: release consumers' last phase
        BAR();
#undef SCOMP
#undef RLDB
    } else {
        // ================= consumer: O += T * P^T =================
        int cq = wid - 4;
        const u16* tbse = tb_f + ((size_t)(cq << 3) << 9);   // uniform base
        short8 tbcA[4][2], tbcB[4][2];

#define RLDT(TB, OFF)                                                                      \
        { _Pragma("unroll")                                                                \
          for (int ci = 0; ci < 4; ++ci) {                                                 \
              _Pragma("unroll")                                                            \
              for (int k2 = 0; k2 < 2; ++k2)                                               \
                  TB[ci][k2] = *(const short8*)(tbse + (OFF)                               \
                                                + ((((ci << 1) + k2)) << 9) + lane8); } }

#define RDP(PFR, SLOT)                                                                     \
    {                                                                                      \
        char* pc = pbase + ((SLOT) << 13);                                                 \
        _Pragma("unroll")                                                                  \
        for (int nj = 0; nj < 4; ++nj) {                                                   \
            PFR[nj][0] = *(const short8*)(pc + PBYTE((nj << 4) + lr, (lg << 3)));          \
            PFR[nj][1] = *(const short8*)(pc + PBYTE((nj << 4) + lr, 32 + (lg << 3)));     \
        }                                                                                  \
    }

#define OMMA(TC, PFR)                                                                      \
    {                                                                                      \
        __builtin_amdgcn_s_setprio(1);                                                     \
        _Pragma("unroll")                                                                  \
        for (int ci = 0; ci < 4; ++ci) {                                                   \
            _Pragma("unroll")                                                              \
            for (int nj = 0; nj < 4; ++nj) {                                               \
                oacc[ci][nj] = MFMA16(TC[ci][0], PFR[nj][0], oacc[ci][nj]);                \
                oacc[ci][nj] = MFMA16(TC[ci][1], PFR[nj][1], oacc[ci][nj]);                \
            }                                                                              \
        }                                                                                  \
        __builtin_amdgcn_s_setprio(0);                                                     \
    }

        RLDT(tbcA, 0);                  // tile 0
        RLDT(tbcB, 16384);              // tile 1
        tbse += 32768;                  // -> tile 2

        f32x4 oacc[4][4];
#pragma unroll
        for (int ci = 0; ci < 4; ++ci)
#pragma unroll
            for (int nj = 0; nj < 4; ++nj) oacc[ci][nj] = zero;
        BAR();

        // main: pp covers ct=4pp (slots 0,1) and ct=4pp+2 (slots 2,3)
        for (int pp = 0; pp < 15; ++pp) {
            {
                short8 pfrA[4][2], pfrB[4][2];
                RDP(pfrA, 0);
                RDP(pfrB, 1);
                OMMA(tbcA, pfrA);
                RLDT(tbcA, 0);
                OMMA(tbcB, pfrB);
                RLDT(tbcB, 16384);
                tbse += 32768;
                BAR();
            }
            {
                short8 pfrA[4][2], pfrB[4][2];
                RDP(pfrA, 2);
                RDP(pfrB, 3);
                OMMA(tbcA, pfrA);
                RLDT(tbcA, 0);
                OMMA(tbcB, pfrB);
                RLDT(tbcB, 16384);
                tbse += 32768;
                BAR();
            }
        }
        // tail ct=60: tiles 60,61 (slots 0,1), reload 62,63
        {
            short8 pfrA[4][2], pfrB[4][2];
            RDP(pfrA, 0);
            RDP(pfrB, 1);
            OMMA(tbcA, pfrA);
            RLDT(tbcA, 0);
            OMMA(tbcB, pfrB);
            RLDT(tbcB, 16384);
            BAR();
        }
        // tail ct=62: tiles 62,63 (slots 2,3)
        {
            short8 pfrA[4][2], pfrB[4][2];
            RDP(pfrA, 2);
            RDP(pfrB, 3);
            OMMA(tbcA, pfrA);
            OMMA(tbcB, pfrB);
            BAR();
        }
#undef OMMA
#undef RDP
#undef RLDT

        // epilogue: write O fp32
#pragma unroll
        for (int ci = 0; ci < 4; ++ci) {
            int c = (cq << 6) + (ci << 4) + (lg << 2);
#pragma unroll
            for (int nj = 0; nj < 4; ++nj) {
                int n = n0 + (nj << 4) + lr;
                float* op = out_b + (size_t)c * 4096 + n;
#pragma unroll
                for (int r = 0; r < 4; ++r) op[(size_t)r * 4096] = oacc[ci][nj][r];
            }
        }
    }
#undef PBYTE
#undef BAR
}

extern "C" void kernel_launch(void* const* d_in, const int* in_sizes, int n_in,
                              void* d_out, int out_size, void* d_ws, size_t ws_size,
                              hipStream_t stream) {
    const float* x = (const float*)d_in[0];     // (4,256,16,16,16) fp32
    const float* W = (const float*)d_in[1];     // (256,256) fp32
    const float* bias = (const float*)d_in[2];  // (256,) fp32
    float* out = (float*)d_out;

    char* ws = (char*)d_ws;
    u16* xff = (u16*)ws;                                   // 8 MiB: xn fragment-major
    u16* tbf = (u16*)(ws + ((size_t)8 << 20));             // 8 MiB: T fragment-major
    u16* Wf = (u16*)(ws + ((size_t)16 << 20));             // 128 KiB: W fragment-major
    float* nrm = (float*)(ws + ((size_t)16 << 20) + (192u << 10));  // 64 KiB

    hipLaunchKernelGGL(k_prep, dim3(256), dim3(256), 0, stream, x, W, xff, Wf, nrm);
    hipLaunchKernelGGL(k_tgemm, dim3(256), dim3(256), 0, stream, Wf, xff, bias, nrm, tbf);
    hipLaunchKernelGGL(k_fused, dim3(256), dim3(512), 0, stream, xff, tbf, out);
}